// Round 2
// baseline (3178.845 us; speedup 1.0000x reference)
//
#include <hip/hip_runtime.h>

constexpr int B_ = 128, S_ = 25, NF_ = 196, ENC_ = 512, ATT_ = 512;
constexpr int H_ = 512, E_ = 256, V_ = 10000, G4_ = 2048;
constexpr int VPAD_ = 10112;  // 79*128

typedef __attribute__((ext_vector_type(8))) __bf16 bf16x8;
typedef __attribute__((ext_vector_type(4))) __bf16 bf16x4;
typedef __attribute__((ext_vector_type(4))) float f32x4;

__device__ __forceinline__ float fast_tanhf(float x) {
    x = fminf(fmaxf(x, -15.f), 15.f);
    float e = __expf(2.f * x);
    return (e - 1.f) / (e + 1.f);
}
__device__ __forceinline__ float fast_sigf(float x) {
    x = fminf(fmaxf(x, -30.f), 30.f);
    return 1.f / (1.f + __expf(-x));
}

// ---------------- f32 -> bf16 converters ----------------
__global__ __launch_bounds__(256) void k_cvt(const float* __restrict__ s,
                                             __bf16* __restrict__ d, int n4) {
    int i = blockIdx.x * 256 + threadIdx.x;
    if (i >= n4) return;
    float4 v = *(const float4*)&s[(size_t)i * 4];
    bf16x4 o;
    o[0] = (__bf16)v.x; o[1] = (__bf16)v.y; o[2] = (__bf16)v.z; o[3] = (__bf16)v.w;
    *(bf16x4*)&d[(size_t)i * 4] = o;
}

// fcw [10000,512] f32 -> padded [10112,512] bf16 (pad rows zero)
__global__ __launch_bounds__(256) void k_cvt_fcw(const float* __restrict__ s,
                                                 __bf16* __restrict__ d) {
    int i = blockIdx.x * 256 + threadIdx.x;   // quad index
    if (i >= VPAD_ * 512 / 4) return;
    int e = i * 4;
    int row = e >> 9;
    bf16x4 o;
    if (row < V_) {
        float4 v = *(const float4*)&s[(size_t)row * 512 + (e & 511)];
        o[0] = (__bf16)v.x; o[1] = (__bf16)v.y; o[2] = (__bf16)v.z; o[3] = (__bf16)v.w;
    } else {
        o[0] = o[1] = o[2] = o[3] = (__bf16)0.f;
    }
    *(bf16x4*)&d[(size_t)e] = o;
}

// ---------------- embeds_all[s*128+b][e] = emb[tok]+pos_emb[s] ----------------
__global__ __launch_bounds__(256) void k_embed(const int* __restrict__ dec,
                                               const float* __restrict__ emb,
                                               const float* __restrict__ pose,
                                               float* __restrict__ embeds) {
    int bx = blockIdx.x;           // = s*128 + b
    int s = bx >> 7, b = bx & 127;
    int e = threadIdx.x;           // E_ == 256
    int tok = dec[b * S_ + s];
    embeds[bx * E_ + e] = emb[tok * E_ + e] + pose[s * E_ + e];
}

// ---------------- mean_enc -> h0 (Hall slot 0), c0 ----------------
__global__ __launch_bounds__(256) void k_init(const float* __restrict__ enc,
                                              const float* __restrict__ ihw, const float* __restrict__ ihb,
                                              const float* __restrict__ icw, const float* __restrict__ icb,
                                              float* __restrict__ Hall, float* __restrict__ cbuf) {
    __shared__ __align__(16) float mean[ENC_];
    int b = blockIdx.x, t = threadIdx.x;
    for (int d = t; d < ENC_; d += 256) {
        float sum = 0.f;
        for (int n = 0; n < NF_; ++n) sum += enc[(b * NF_ + n) * ENC_ + d];
        mean[d] = sum * (1.f / NF_);
    }
    __syncthreads();
    for (int j = t; j < H_; j += 256) {
        float ah = 0.f, ac = 0.f;
        const float4* wh = (const float4*)&ihw[j * ENC_];
        const float4* wc = (const float4*)&icw[j * ENC_];
        for (int d4 = 0; d4 < ENC_ / 4; ++d4) {
            float4 m4 = *(const float4*)&mean[d4 * 4];
            float4 h4 = wh[d4], c4 = wc[d4];
            ah += m4.x * h4.x + m4.y * h4.y + m4.z * h4.z + m4.w * h4.w;
            ac += m4.x * c4.x + m4.y * c4.y + m4.z * c4.z + m4.w * c4.w;
        }
        Hall[b * H_ + j] = ah + ihb[j];
        cbuf[b * H_ + j] = ac + icb[j];
    }
}

// ---------------- 128x128 tiled f32 GEMM (gates_pre only) ----------------
template<bool REMAP>
__global__ __launch_bounds__(256) void k_gemm128(
    const float* __restrict__ A, int lda,
    const float* __restrict__ Bm, int ldb,
    const float* __restrict__ bias1, const float* __restrict__ bias2,
    float* __restrict__ C, int ldc, int N, int K) {
    __shared__ float As[16][132];
    __shared__ float Bs[16][132];
    int tid = threadIdx.x;
    int m0 = blockIdx.x * 128, n0 = blockIdx.y * 128;
    int tm = (tid >> 4) * 8, tn = (tid & 15) * 8;
    float acc[8][8] = {};
    for (int k0 = 0; k0 < K; k0 += 16) {
#pragma unroll
        for (int it = 0; it < 2; ++it) {
            int q = tid + it * 256;
            int row = q >> 2, kq = (q & 3) << 2;
            float4 av = *(const float4*)&A[(m0 + row) * lda + k0 + kq];
            As[kq + 0][row] = av.x; As[kq + 1][row] = av.y;
            As[kq + 2][row] = av.z; As[kq + 3][row] = av.w;
            float4 bv = make_float4(0.f, 0.f, 0.f, 0.f);
            if (n0 + row < N) bv = *(const float4*)&Bm[(n0 + row) * ldb + k0 + kq];
            Bs[kq + 0][row] = bv.x; Bs[kq + 1][row] = bv.y;
            Bs[kq + 2][row] = bv.z; Bs[kq + 3][row] = bv.w;
        }
        __syncthreads();
#pragma unroll
        for (int kk = 0; kk < 16; ++kk) {
            float4 a0 = *(const float4*)&As[kk][tm];
            float4 a1 = *(const float4*)&As[kk][tm + 4];
            float4 b0 = *(const float4*)&Bs[kk][tn];
            float4 b1 = *(const float4*)&Bs[kk][tn + 4];
            float a[8] = {a0.x, a0.y, a0.z, a0.w, a1.x, a1.y, a1.z, a1.w};
            float bb[8] = {b0.x, b0.y, b0.z, b0.w, b1.x, b1.y, b1.z, b1.w};
#pragma unroll
            for (int i = 0; i < 8; ++i)
#pragma unroll
                for (int j = 0; j < 8; ++j) acc[i][j] += a[i] * bb[j];
        }
        __syncthreads();
    }
#pragma unroll
    for (int i = 0; i < 8; ++i) {
        int m = m0 + tm + i;
        int orow = REMAP ? ((m & 127) * S_ + (m >> 7)) : m;
#pragma unroll
        for (int j = 0; j < 8; ++j) {
            int n = n0 + tn + j;
            if (n < N) {
                float v = acc[i][j];
                if (bias1) v += bias1[n];
                if (bias2) v += bias2[n];
                C[orow * ldc + n] = v;
            }
        }
    }
}

// ---------------- bf16 MFMA GEMM: C[m,n] = sum_k A[m,k]*Bm[n,k] + bias[n] ----------------
// A:[M,K] bf16, Bm:[Npad,K] bf16. M%128==0, Npad%128==0, K%64==0.
// MODE 0: f32 out with remap row (s*128+b -> b*25+s), guard n<Nreal (fcn)
// MODE 1: bf16 out (u_hs)
template<int MODE>
__global__ __launch_bounds__(256) void k_mfma_gemm(
    const __bf16* __restrict__ A, const __bf16* __restrict__ Bm,
    const float* __restrict__ bias, void* __restrict__ Cout,
    int K, int Nreal, int ldc) {
    __shared__ __align__(16) __bf16 As[128 * 64];
    __shared__ __align__(16) __bf16 Bs[128 * 64];
    int tid = threadIdx.x;
    int lane = tid & 63, w = tid >> 6;
    int m0 = blockIdx.x * 128, n0 = blockIdx.y * 128;
    int wm = (w & 1) * 64, wn = (w >> 1) * 64;
    f32x4 acc[4][4] = {};
    int srow = tid >> 3;          // 0..31 within 32-row chunk
    int ke = (tid & 7) * 8;       // k element offset 0..56
    int kgw = tid & 7;            // k-group for writes

    for (int k0 = 0; k0 < K; k0 += 64) {
#pragma unroll
        for (int it = 0; it < 4; ++it) {
            int row = it * 32 + srow;
            bf16x8 av = *(const bf16x8*)(A + (size_t)(m0 + row) * K + k0 + ke);
            bf16x8 bv = *(const bf16x8*)(Bm + (size_t)(n0 + row) * K + k0 + ke);
            int kg = kgw ^ (row & 7);          // XOR swizzle (T2)
            *(bf16x8*)&As[row * 64 + kg * 8] = av;
            *(bf16x8*)&Bs[row * 64 + kg * 8] = bv;
        }
        __syncthreads();
        bf16x8 af[4][2], bfr[4][2];
#pragma unroll
        for (int f = 0; f < 4; ++f) {
#pragma unroll
            for (int ks = 0; ks < 2; ++ks) {
                int ra = wm + f * 16 + (lane & 15);
                int rb = wn + f * 16 + (lane & 15);
                int kgl = ks * 4 + (lane >> 4);
                af[f][ks]  = *(const bf16x8*)&As[ra * 64 + (kgl ^ (ra & 7)) * 8];
                bfr[f][ks] = *(const bf16x8*)&Bs[rb * 64 + (kgl ^ (rb & 7)) * 8];
            }
        }
#pragma unroll
        for (int fm = 0; fm < 4; ++fm)
#pragma unroll
            for (int fn = 0; fn < 4; ++fn)
#pragma unroll
                for (int ks = 0; ks < 2; ++ks)
                    acc[fm][fn] = __builtin_amdgcn_mfma_f32_16x16x32_bf16(
                        af[fm][ks], bfr[fn][ks], acc[fm][fn], 0, 0, 0);
        __syncthreads();
    }
    // C/D layout: col = lane&15, row = (lane>>4)*4 + reg  [m89]
    int cm = (lane >> 4) * 4, cn = lane & 15;
#pragma unroll
    for (int fm = 0; fm < 4; ++fm) {
#pragma unroll
        for (int fn = 0; fn < 4; ++fn) {
#pragma unroll
            for (int r = 0; r < 4; ++r) {
                int gm = m0 + wm + fm * 16 + cm + r;
                int gn = n0 + wn + fn * 16 + cn;
                float v = acc[fm][fn][r];
                if (MODE == 0) {
                    if (gn < Nreal) {
                        int orow = (gm & 127) * S_ + (gm >> 7);
                        ((float*)Cout)[(size_t)orow * ldc + gn] = v + bias[gn];
                    }
                } else {
                    ((__bf16*)Cout)[(size_t)gm * ldc + gn] = (__bf16)(v + bias[gn]);
                }
            }
        }
    }
}

// ---------------- fused per-step attention: w_ah + scores + softmax + context ----------------
__global__ __launch_bounds__(256) void k_attn_fused(
    const __bf16* __restrict__ u_hs, const float* __restrict__ enc,
    const float* __restrict__ h, const float* __restrict__ Ww,
    const float* __restrict__ Wb, const float* __restrict__ Aw,
    const float* __restrict__ Ab, float* __restrict__ ctx,
    float* __restrict__ alphas, int s) {
    __shared__ __align__(16) float hs[512];
    __shared__ float wah[512];
    __shared__ float aw[512];
    __shared__ float sc[224];
    __shared__ float red[256];
    int b = blockIdx.x, t = threadIdx.x;
    float2 h2 = *(const float2*)&h[b * 512 + t * 2];
    hs[t * 2] = h2.x; hs[t * 2 + 1] = h2.y;
    aw[t] = Aw[t]; aw[t + 256] = Aw[t + 256];
    __syncthreads();
    // w_ah[j] for j = t, t+256
    float acc0 = Wb[t], acc1 = Wb[t + 256];
    const float4* h4 = (const float4*)hs;
    const float4* w0 = (const float4*)&Ww[t * 512];
    const float4* w1 = (const float4*)&Ww[(t + 256) * 512];
#pragma unroll 4
    for (int k4 = 0; k4 < 128; ++k4) {
        float4 hv = h4[k4];
        float4 a = w0[k4], c = w1[k4];
        acc0 += hv.x * a.x + hv.y * a.y + hv.z * a.z + hv.w * a.w;
        acc1 += hv.x * c.x + hv.y * c.y + hv.z * c.z + hv.w * c.w;
    }
    wah[t] = acc0; wah[t + 256] = acc1;
    __syncthreads();
    // scores
    int wave = t >> 6, lane = t & 63;
    for (int n = wave; n < NF_; n += 4) {
        bf16x8 u8 = *(const bf16x8*)&u_hs[((size_t)(b * NF_ + n)) * 512 + lane * 8];
        int a0 = lane * 8;
        float acc = 0.f;
#pragma unroll
        for (int i = 0; i < 8; ++i)
            acc += fast_tanhf((float)u8[i] + wah[a0 + i]) * aw[a0 + i];
#pragma unroll
        for (int off = 32; off > 0; off >>= 1) acc += __shfl_xor(acc, off);
        if (lane == 0) sc[n] = acc + Ab[0];
    }
    __syncthreads();
    // softmax over 196
    red[t] = (t < NF_) ? sc[t] : -1e30f;
    __syncthreads();
    for (int off = 128; off > 0; off >>= 1) {
        if (t < off) red[t] = fmaxf(red[t], red[t + off]);
        __syncthreads();
    }
    float mx = red[0];
    __syncthreads();
    float e = (t < NF_) ? __expf(sc[t] - mx) : 0.f;
    red[t] = e;
    __syncthreads();
    for (int off = 128; off > 0; off >>= 1) {
        if (t < off) red[t] += red[t + off];
        __syncthreads();
    }
    float inv = 1.f / red[0];
    __syncthreads();
    if (t < NF_) {
        float a = e * inv;
        sc[t] = a;
        alphas[(b * S_ + s) * NF_ + t] = a;
    }
    __syncthreads();
    // context
    float c0 = 0.f, c1 = 0.f;
#pragma unroll 4
    for (int n = 0; n < NF_; ++n) {
        float a = sc[n];
        c0 += a * enc[(b * NF_ + n) * ENC_ + t];
        c1 += a * enc[(b * NF_ + n) * ENC_ + t + 256];
    }
    ctx[b * ENC_ + t] = c0;
    ctx[b * ENC_ + t + 256] = c1;
}

// ---------------- fused gates GEMM (K=1024) + LSTM pointwise ----------------
// grid (4, 64): b0 = bx*32, j0 = by*8. Local cols c in [0,32): gate g=c>>3, jj=c&7.
__global__ __launch_bounds__(256) void k_gates_lstm(
    const float* __restrict__ ctx, const float* __restrict__ hprev,
    const float* __restrict__ W_ih, const float* __restrict__ W_hh,
    const float* __restrict__ gatespre, float* __restrict__ cbuf,
    float* __restrict__ Hall, __bf16* __restrict__ Hall_bf, int s) {
    __shared__ __align__(16) float As[64][32];   // [k][b]
    __shared__ __align__(16) float Bs[64][32];   // [k][c]
    int tid = threadIdx.x;
    int b0 = blockIdx.x * 32;
    int j0 = blockIdx.y * 8;
    int tm = (tid >> 4) * 2, tn = (tid & 15) * 2;
    float a00 = 0.f, a01 = 0.f, a10 = 0.f, a11 = 0.f;
    int r = tid >> 3;              // 0..31 (stage row / col)
    int kq = (tid & 7) * 8;        // 0..56
    int wr = (r >> 3) * 512 + j0 + (r & 7);     // weight row for col r
    for (int k0 = 0; k0 < 1024; k0 += 64) {
        const float* asrc = (k0 < 512) ? &ctx[(b0 + r) * 512 + k0 + kq]
                                       : &hprev[(b0 + r) * 512 + (k0 - 512) + kq];
        const float* bsrc = (k0 < 512) ? &W_ih[wr * 768 + 256 + k0 + kq]
                                       : &W_hh[wr * 512 + (k0 - 512) + kq];
        float4 av0 = *(const float4*)asrc;
        float4 av1 = *(const float4*)(asrc + 4);
        float4 bv0 = *(const float4*)bsrc;
        float4 bv1 = *(const float4*)(bsrc + 4);
        As[kq + 0][r] = av0.x; As[kq + 1][r] = av0.y; As[kq + 2][r] = av0.z; As[kq + 3][r] = av0.w;
        As[kq + 4][r] = av1.x; As[kq + 5][r] = av1.y; As[kq + 6][r] = av1.z; As[kq + 7][r] = av1.w;
        Bs[kq + 0][r] = bv0.x; Bs[kq + 1][r] = bv0.y; Bs[kq + 2][r] = bv0.z; Bs[kq + 3][r] = bv0.w;
        Bs[kq + 4][r] = bv1.x; Bs[kq + 5][r] = bv1.y; Bs[kq + 6][r] = bv1.z; Bs[kq + 7][r] = bv1.w;
        __syncthreads();
#pragma unroll
        for (int kk = 0; kk < 64; ++kk) {
            float2 a2 = *(const float2*)&As[kk][tm];
            float2 b2 = *(const float2*)&Bs[kk][tn];
            a00 += a2.x * b2.x; a01 += a2.x * b2.y;
            a10 += a2.y * b2.x; a11 += a2.y * b2.y;
        }
        __syncthreads();
    }
    float (*Gs)[32] = (float(*)[32])As;
    Gs[tm + 0][tn + 0] = a00; Gs[tm + 0][tn + 1] = a01;
    Gs[tm + 1][tn + 0] = a10; Gs[tm + 1][tn + 1] = a11;
    __syncthreads();
    int b = tid >> 3, jj = tid & 7;
    int gb = b0 + b, gj = j0 + jj;
    float q[4];
#pragma unroll
    for (int g = 0; g < 4; ++g)
        q[g] = Gs[b][g * 8 + jj] + gatespre[(size_t)(s * B_ + gb) * G4_ + g * 512 + gj];
    float ig = fast_sigf(q[0]), fg = fast_sigf(q[1]);
    float gg = fast_tanhf(q[2]), og = fast_sigf(q[3]);
    int ci = gb * 512 + gj;
    float cn = fg * cbuf[ci] + ig * gg;
    float hn = og * fast_tanhf(cn);
    cbuf[ci] = cn;
    Hall[(s + 1) * (B_ * H_) + ci] = hn;
    Hall_bf[(s + 1) * (B_ * H_) + ci] = (__bf16)hn;
}

extern "C" void kernel_launch(void* const* d_in, const int* in_sizes, int n_in,
                              void* d_out, int out_size, void* d_ws, size_t ws_size,
                              hipStream_t stream) {
    const int*   dec  = (const int*)d_in[0];
    const float* enc  = (const float*)d_in[1];
    const float* emb  = (const float*)d_in[2];
    const float* pose = (const float*)d_in[3];
    const float* Uw   = (const float*)d_in[4];
    const float* Ub   = (const float*)d_in[5];
    const float* Ww   = (const float*)d_in[6];
    const float* Wb   = (const float*)d_in[7];
    const float* Aw   = (const float*)d_in[8];
    const float* Ab   = (const float*)d_in[9];
    const float* ihw  = (const float*)d_in[10];
    const float* ihb  = (const float*)d_in[11];
    const float* icw  = (const float*)d_in[12];
    const float* icb  = (const float*)d_in[13];
    const float* W_ih = (const float*)d_in[14];
    const float* W_hh = (const float*)d_in[15];
    const float* b_ih = (const float*)d_in[16];
    const float* b_hh = (const float*)d_in[17];
    const float* fcw  = (const float*)d_in[18];
    const float* fcb  = (const float*)d_in[19];
    float* out = (float*)d_out;
    char*  wsb = (char*)d_ws;

    // ---- workspace layout (bytes), ~76.8 MB ----
    size_t o = 0;
    __bf16* u_hs_bf = (__bf16*)(wsb + o); o += (size_t)25088 * 512 * 2;      // 25,690,112
    float*  gatespre = (float*)(wsb + o);                                     // 26,214,400
    __bf16* enc_bf   = (__bf16*)(wsb + o);   // ALIAS: dead after u_hs GEMM
    o += (size_t)3200 * 2048 * 4;
    float*  embeds  = (float*)(wsb + o); o += (size_t)3200 * 256 * 4;        //  3,276,800
    float*  Hall    = (float*)(wsb + o); o += (size_t)26 * 65536 * 4;        //  6,815,744
    __bf16* Hall_bf = (__bf16*)(wsb + o); o += (size_t)26 * 65536 * 2;       //  3,407,872
    float*  cbuf    = (float*)(wsb + o); o += (size_t)65536 * 4;             //    262,144
    float*  ctx     = (float*)(wsb + o); o += (size_t)65536 * 4;             //    262,144
    __bf16* fcw_bf  = (__bf16*)(wsb + o); o += (size_t)VPAD_ * 512 * 2;      // 10,354,688
    __bf16* Uw_bf   = (__bf16*)(wsb + o); o += (size_t)262144 * 2;           //    524,288

    // ---- conversions + loop-invariant precomputes ----
    k_cvt<<<12544, 256, 0, stream>>>(enc, enc_bf, 3211264);
    k_cvt<<<256, 256, 0, stream>>>(Uw, Uw_bf, 65536);
    k_cvt_fcw<<<5056, 256, 0, stream>>>(fcw, fcw_bf);
    k_embed<<<S_ * B_, 256, 0, stream>>>(dec, emb, pose, embeds);
    k_init<<<B_, 256, 0, stream>>>(enc, ihw, ihb, icw, icb, Hall, cbuf);

    // u_hs = enc @ Uw^T + Ub -> bf16 [25088,512]
    k_mfma_gemm<1><<<dim3(196, 4), 256, 0, stream>>>(enc_bf, Uw_bf, Ub, u_hs_bf, 512, 512, 512);
    // gates_pre = embeds @ W_ih[:, :256]^T + b_ih + b_hh : f32 [3200,2048]  (overwrites enc_bf alias)
    k_gemm128<false><<<dim3(25, 16), 256, 0, stream>>>(embeds, E_, W_ih, E_ + ENC_, b_ih, b_hh,
                                                       gatespre, G4_, G4_, E_);

    for (int s = 0; s < S_; ++s) {
        const float* h = Hall + (size_t)s * (B_ * H_);
        k_attn_fused<<<B_, 256, 0, stream>>>(u_hs_bf, enc, h, Ww, Wb, Aw, Ab,
                                             ctx, out + 32000000, s);
        k_gates_lstm<<<dim3(4, 64), 256, 0, stream>>>(ctx, h, W_ih, W_hh, gatespre,
                                                      cbuf, Hall, Hall_bf, s);
    }

    // outs = Hall_bf[1..25] @ fcn_w^T + fcn_b -> f32 [B,S,V]
    k_mfma_gemm<0><<<dim3(25, 79), 256, 0, stream>>>(Hall_bf + B_ * H_, fcw_bf, fcb, out,
                                                     512, V_, V_);
}